// Round 9
// baseline (188.851 us; speedup 1.0000x reference)
//
#include <hip/hip_runtime.h>
#include <hip/hip_bf16.h>

typedef __attribute__((ext_vector_type(8))) short short8;
typedef __attribute__((ext_vector_type(4))) float f32x4;
typedef __attribute__((ext_vector_type(8))) unsigned short ushort8;
typedef __attribute__((ext_vector_type(2))) unsigned uint2v;

#define LOG2E 1.44269504088896340736f

__device__ __forceinline__ float fexp2(float x) {
  float r;
  asm("v_exp_f32 %0, %1" : "=v"(r) : "v"(x));   // 2^x, guaranteed native
  return r;
}
__device__ __forceinline__ unsigned cvtpk(float lo, float hi) {
  unsigned r;
  asm("v_cvt_pk_bf16_f32 %0, %1, %2" : "=v"(r) : "v"(lo), "v"(hi));
  return r;
}
__device__ __forceinline__ void pswap32(unsigned &a, unsigned &b) {
#if __has_builtin(__builtin_amdgcn_permlane32_swap)
  uint2v r = __builtin_amdgcn_permlane32_swap(a, b, false, false);
  a = r[0]; b = r[1];
#else
  asm("v_permlane32_swap_b32 %0, %1" : "+v"(a), "+v"(b));
#endif
}
__device__ __forceinline__ void pswap16(unsigned &a, unsigned &b) {
#if __has_builtin(__builtin_amdgcn_permlane16_swap)
  uint2v r = __builtin_amdgcn_permlane16_swap(a, b, false, false);
  a = r[0]; b = r[1];
#else
  asm("v_permlane16_swap_b32 %0, %1" : "+v"(a), "+v"(b));
#endif
}
__device__ __forceinline__ float redsum16(float x) {
  unsigned a = __float_as_uint(x), b = a;
  pswap16(a, b);
  return __uint_as_float(a) + __uint_as_float(b);
}
__device__ __forceinline__ float redsum32(float x) {
  unsigned a = __float_as_uint(x), b = a;
  pswap32(a, b);
  return __uint_as_float(a) + __uint_as_float(b);
}
__device__ __forceinline__ void gload_lds16(const unsigned short* g, unsigned short* l) {
  __builtin_amdgcn_global_load_lds(
      (const __attribute__((address_space(1))) unsigned int*)g,
      (__attribute__((address_space(3))) unsigned int*)l, 16, 0, 0);
}
__device__ __forceinline__ int swzK(int r) {
  return ((r & 3) | (((r >> 3) & 1) << 2)) << 3;
}

// ------- MFMA Q/K/V projection; writes Q,K as [bh][n][d], V as V^T [bh][d][n] --
__global__ __launch_bounds__(256) void proj_kernel(
    const float* __restrict__ x,
    const float* __restrict__ Wq, const float* __restrict__ Wk,
    const float* __restrict__ Wv,
    unsigned short* __restrict__ Qo, unsigned short* __restrict__ Ko,
    unsigned short* __restrict__ Vto)
{
  const int tid = threadIdx.x, lane = tid & 63, w = tid >> 6;
  const int r15 = lane & 15, G = lane >> 4;
  const int bh = blockIdx.x >> 4, nt = blockIdx.x & 15;
  const int b = bh >> 3, h = bh & 7;
  const int n0 = nt * 256 + w * 64;

  short8 xf[4][2];
  #pragma unroll
  for (int ct = 0; ct < 4; ++ct) {
    const int n = n0 + ct * 16 + r15;
    const float* xr = x + ((size_t)((b * 4096 + n) * 8 + h)) * 64;
    #pragma unroll
    for (int s = 0; s < 2; ++s) {
      const f32x4 f0 = *(const f32x4*)&xr[s * 32 + G * 8];
      const f32x4 f1 = *(const f32x4*)&xr[s * 32 + G * 8 + 4];
      union { unsigned u[4]; short8 s8; } uu;
      uu.u[0] = cvtpk(f0[0], f0[1]); uu.u[1] = cvtpk(f0[2], f0[3]);
      uu.u[2] = cvtpk(f1[0], f1[1]); uu.u[3] = cvtpk(f1[2], f1[3]);
      xf[ct][s] = uu.s8;
    }
  }

  const size_t obase = (size_t)bh * (4096 * 64);

  #pragma unroll
  for (int wi = 0; wi < 2; ++wi) {
    const float* W = wi ? Wk : Wq;
    unsigned short* O = wi ? Ko : Qo;
    const float sc = wi ? 1.0f : 0.125f * LOG2E;
    short8 wf[4][2];
    #pragma unroll
    for (int ft = 0; ft < 4; ++ft)
      #pragma unroll
      for (int s = 0; s < 2; ++s) {
        union { unsigned u[4]; short8 s8; } uu;
        #pragma unroll
        for (int jj = 0; jj < 4; ++jj) {
          const int k0 = s * 32 + G * 8 + jj * 2;
          uu.u[jj] = cvtpk(W[k0 * 64 + ft * 16 + r15] * sc,
                           W[(k0 + 1) * 64 + ft * 16 + r15] * sc);
        }
        wf[ft][s] = uu.s8;
      }
    f32x4 acc[4][4];
    #pragma unroll
    for (int ft = 0; ft < 4; ++ft)
      #pragma unroll
      for (int ct = 0; ct < 4; ++ct) acc[ft][ct] = (f32x4){0.f, 0.f, 0.f, 0.f};
    #pragma unroll
    for (int s = 0; s < 2; ++s)
      #pragma unroll
      for (int ft = 0; ft < 4; ++ft)
        #pragma unroll
        for (int ct = 0; ct < 4; ++ct)
          acc[ft][ct] = __builtin_amdgcn_mfma_f32_16x16x32_bf16(
              wf[ft][s], xf[ct][s], acc[ft][ct], 0, 0, 0);
    #pragma unroll
    for (int ft = 0; ft < 4; ++ft)
      #pragma unroll
      for (int ct = 0; ct < 4; ++ct) {
        uint2v pk;
        pk[0] = cvtpk(acc[ft][ct][0], acc[ft][ct][1]);
        pk[1] = cvtpk(acc[ft][ct][2], acc[ft][ct][3]);
        *(uint2v*)&O[obase + (size_t)(n0 + ct * 16 + r15) * 64 + ft * 16 + G * 4] = pk;
      }
  }

  {
    short8 wf[4][2];
    #pragma unroll
    for (int ft = 0; ft < 4; ++ft)
      #pragma unroll
      for (int s = 0; s < 2; ++s) {
        union { unsigned u[4]; short8 s8; } uu;
        #pragma unroll
        for (int jj = 0; jj < 4; ++jj) {
          const int k0 = s * 32 + G * 8 + jj * 2;
          uu.u[jj] = cvtpk(Wv[k0 * 64 + ft * 16 + r15], Wv[(k0 + 1) * 64 + ft * 16 + r15]);
        }
        wf[ft][s] = uu.s8;
      }
    f32x4 acc[4][4];
    #pragma unroll
    for (int ct = 0; ct < 4; ++ct)
      #pragma unroll
      for (int ft = 0; ft < 4; ++ft) acc[ct][ft] = (f32x4){0.f, 0.f, 0.f, 0.f};
    #pragma unroll
    for (int s = 0; s < 2; ++s)
      #pragma unroll
      for (int ct = 0; ct < 4; ++ct)
        #pragma unroll
        for (int ft = 0; ft < 4; ++ft)
          acc[ct][ft] = __builtin_amdgcn_mfma_f32_16x16x32_bf16(
              xf[ct][s], wf[ft][s], acc[ct][ft], 0, 0, 0);
    #pragma unroll
    for (int ct = 0; ct < 4; ++ct)
      #pragma unroll
      for (int ft = 0; ft < 4; ++ft) {
        uint2v pk;
        pk[0] = cvtpk(acc[ct][ft][0], acc[ct][ft][1]);
        pk[1] = cvtpk(acc[ct][ft][2], acc[ct][ft][3]);
        *(uint2v*)&Vto[obase + (size_t)(ft * 16 + r15) * 4096 + n0 + ct * 16 + G * 4] = pk;
      }
  }
}

// -------- flash attention, swapped QK^T, static-shift softmax, fused Wo -------
// grid 1024 = 32 bh x 32 qtiles(128). 2 waves x 64 q-rows (4 sub-tiles of 16).
// 64q/wave halves LDS-pipe traffic per unit work; 32KB LDS -> 5 blocks/CU.
// R4-proven sync skeleton: stage next tile at top, ONE __syncthreads per tile.
__global__ __launch_bounds__(128) void attn_kernel(
    const unsigned short* __restrict__ Q, const unsigned short* __restrict__ K,
    const unsigned short* __restrict__ Vt, const float* __restrict__ Wo,
    const float* __restrict__ bo, float* __restrict__ out)
{
  // 32 KB: [ K dbuf 16KB | V dbuf 16KB ]; reused as 2 x 8KB fp32 O tiles at epilogue
  __shared__ __align__(16) unsigned short SM[16384];

  const int tid = threadIdx.x;
  const int lane = tid & 63, w = tid >> 6;          // w in {0,1}
  const int r15 = lane & 15, G = lane >> 4;

  int bid = blockIdx.x;
  bid = (bid & 7) * 128 + (bid >> 3);               // XCD swizzle (1024 % 8 == 0)
  const int bh = bid >> 5, qt128 = bid & 31;

  const unsigned short* Qb = Q + (size_t)bh * (4096 * 64);
  const unsigned short* Kb = K + (size_t)bh * (4096 * 64);
  const unsigned short* Vb = Vt + (size_t)bh * (64 * 4096);
  const int q0w = qt128 * 128 + w * 64;

  // Q fragments (B-operand layout): lane holds Q[q=lane&15][G*8+j], 4 sub-tiles
  short8 qf[4][2];
  #pragma unroll
  for (int qt = 0; qt < 4; ++qt) {
    const unsigned short* qr = Qb + (size_t)(q0w + qt * 16 + r15) * 64;
    qf[qt][0] = *(const short8*)&qr[G * 8];
    qf[qt][1] = *(const short8*)&qr[32 + G * 8];
  }

  f32x4 oacc[4][4];
  #pragma unroll
  for (int qt = 0; qt < 4; ++qt)
    #pragma unroll
    for (int t = 0; t < 4; ++t) oacc[qt][t] = (f32x4){0.f, 0.f, 0.f, 0.f};
  float lsum[4] = {0.f, 0.f, 0.f, 0.f};

  // hoisted LDS read offsets
  int kro[4][2], vro[4][2];
  {
    const int Rr = r15 >> 2, gg = r15 & 3;
    #pragma unroll
    for (int t = 0; t < 4; ++t) {
      const int row = gg + ((t & 1) << 2) + ((Rr & 1) << 3) + ((t >> 1) << 4) + ((Rr >> 1) << 5);
      const int sw = swzK(row);
      kro[t][0] = row * 64 + ((G * 8) ^ sw);
      kro[t][1] = row * 64 + ((32 + G * 8) ^ sw);
      const int vrow = t * 16 + r15;
      const int vs = (vrow & 7) << 3;
      vro[t][0] = vrow * 64 + ((G * 8) ^ vs);
      vro[t][1] = vrow * 64 + ((32 + G * 8) ^ vs);
    }
  }

  // staging: 8 segments of 512 elems per tile; wave w owns segs 4w..4w+3.
  const int segb = w * 4;
  int koffs[4], voffs[4], ksegd[4], vsegd[4];
  const int c8 = (lane & 7) * 8;
  #pragma unroll
  for (int j = 0; j < 4; ++j) {
    const int kr = (segb + j) * 8 + (lane >> 3);
    koffs[j] = kr * 64 + (c8 ^ swzK(kr));
    voffs[j] = kr * 4096 + (c8 ^ ((kr & 7) << 3));
    ksegd[j] = (segb + j) * 512;
    vsegd[j] = 8192 + (segb + j) * 512;
  }

  #pragma unroll
  for (int j = 0; j < 4; ++j) {
    gload_lds16(Kb + koffs[j], &SM[ksegd[j]]);
    gload_lds16(Vb + voffs[j], &SM[vsegd[j]]);
  }
  __syncthreads();

  int buf = 0;
  for (int kt = 0; kt < 64; ++kt) {
    if (kt < 63) {
      const int ko = (kt + 1) * 4096;
      const int vo = (kt + 1) * 64;
      const int bo2 = (buf ^ 1) * 4096;
      #pragma unroll
      for (int j = 0; j < 4; ++j) {
        gload_lds16(Kb + ko + koffs[j], &SM[bo2 + ksegd[j]]);
        gload_lds16(Vb + vo + voffs[j], &SM[bo2 + vsegd[j]]);
      }
    }

    const unsigned short* Kc = &SM[buf * 4096];
    const unsigned short* Vc = &SM[8192 + buf * 4096];

    // ---- S = K·Q (static shift; 4 independent q sub-tiles share kf reads) ----
    f32x4 s[4][4];
    #pragma unroll
    for (int t = 0; t < 4; ++t) {
      const short8 kf0 = *(const short8*)&Kc[kro[t][0]];
      const short8 kf1 = *(const short8*)&Kc[kro[t][1]];
      #pragma unroll
      for (int qt = 0; qt < 4; ++qt) {
        f32x4 z = (f32x4){0.f, 0.f, 0.f, 0.f};
        z = __builtin_amdgcn_mfma_f32_16x16x32_bf16(kf0, qf[qt][0], z, 0, 0, 0);
        s[qt][t] = __builtin_amdgcn_mfma_f32_16x16x32_bf16(kf1, qf[qt][1], z, 0, 0, 0);
      }
    }

    // ---- softmax numerator: p = exp2(s); pack; permlane half-exchange ----
    short8 pa[4][2];
    #pragma unroll
    for (int qt = 0; qt < 4; ++qt) {
      float p[4][4];
      #pragma unroll
      for (int t = 0; t < 4; ++t)
        #pragma unroll
        for (int g = 0; g < 4; ++g) p[t][g] = fexp2(s[qt][t][g]);
      const float r0 = (p[0][0] + p[0][1]) + (p[0][2] + p[0][3]);
      const float r1 = (p[1][0] + p[1][1]) + (p[1][2] + p[1][3]);
      const float r2 = (p[2][0] + p[2][1]) + (p[2][2] + p[2][3]);
      const float r3 = (p[3][0] + p[3][1]) + (p[3][2] + p[3][3]);
      lsum[qt] += (r0 + r1) + (r2 + r3);

      unsigned wA[4], wB[4];
      wA[0] = cvtpk(p[0][0], p[0][1]); wA[1] = cvtpk(p[0][2], p[0][3]);
      wA[2] = cvtpk(p[1][0], p[1][1]); wA[3] = cvtpk(p[1][2], p[1][3]);
      wB[0] = cvtpk(p[2][0], p[2][1]); wB[1] = cvtpk(p[2][2], p[2][3]);
      wB[2] = cvtpk(p[3][0], p[3][1]); wB[3] = cvtpk(p[3][2], p[3][3]);
      union { unsigned u[4]; short8 s8; } fa, fb;
      #pragma unroll
      for (int i = 0; i < 4; ++i) {
        pswap32(wA[i], wB[i]);
        fa.u[i] = wA[i];
        fb.u[i] = wB[i];
      }
      pa[qt][0] = fa.s8;
      pa[qt][1] = fb.s8;
    }

    // ---- O += P V  (4 q sub-tiles share vb reads) ----
    #pragma unroll
    for (int t = 0; t < 4; ++t) {
      const short8 vb0 = *(const short8*)&Vc[vro[t][0]];
      const short8 vb1 = *(const short8*)&Vc[vro[t][1]];
      #pragma unroll
      for (int qt = 0; qt < 4; ++qt) {
        oacc[qt][t] = __builtin_amdgcn_mfma_f32_16x16x32_bf16(pa[qt][0], vb0, oacc[qt][t], 0, 0, 0);
        oacc[qt][t] = __builtin_amdgcn_mfma_f32_16x16x32_bf16(pa[qt][1], vb1, oacc[qt][t], 0, 0, 0);
      }
    }
    __syncthreads();
    buf ^= 1;
  }

  // ---- fused epilogue (two per-wave passes of 32 q each): O·Wo + bo -> out ----
  float lt[4];
  #pragma unroll
  for (int qt = 0; qt < 4; ++qt) {
    float l = lsum[qt];
    l = redsum16(l);
    l = redsum32(l);
    lt[qt] = l;
  }

  short8 wof[4][2];
  #pragma unroll
  for (int nt = 0; nt < 4; ++nt)
    #pragma unroll
    for (int st = 0; st < 2; ++st) {
      union { unsigned u[4]; short8 s8; } uu;
      #pragma unroll
      for (int jj = 0; jj < 4; ++jj) {
        const int k0 = st * 32 + G * 8 + jj * 2;
        uu.u[jj] = cvtpk(Wo[k0 * 64 + nt * 16 + r15], Wo[(k0 + 1) * 64 + nt * 16 + r15]);
      }
      wof[nt][st] = uu.s8;
    }
  float bov[4];
  #pragma unroll
  for (int nt = 0; nt < 4; ++nt) bov[nt] = bo[nt * 16 + r15];

  float* Ol = (float*)&SM[0] + w * 2048;   // per-wave 32 q x 64 d, swizzled cols
  const int b = bh >> 3, hh = bh & 7;

  #pragma unroll
  for (int pass = 0; pass < 2; ++pass) {
    #pragma unroll
    for (int ql = 0; ql < 2; ++ql) {
      const int qt = pass * 2 + ql;
      float li[4];
      #pragma unroll
      for (int g = 0; g < 4; ++g) li[g] = __builtin_amdgcn_rcpf(__shfl(lt[qt], G * 4 + g));
      #pragma unroll
      for (int t = 0; t < 4; ++t)
        #pragma unroll
        for (int g = 0; g < 4; ++g) {
          const int q = ql * 16 + G * 4 + g;
          const int d = t * 16 + r15;
          Ol[q * 64 + (d ^ ((q & 7) << 3))] = oacc[qt][t][g] * li[g];
        }
    }
    // same-wave LDS RAW: compiler inserts lgkmcnt waits; regions are per-wave
    #pragma unroll
    for (int ql = 0; ql < 2; ++ql) {
      const int qt = pass * 2 + ql;
      short8 af[2];
      #pragma unroll
      for (int st = 0; st < 2; ++st) {
        const int row = ql * 16 + r15;
        const int c = (st * 32 + G * 8) ^ ((row & 7) << 3);
        const f32x4 f0 = *(const f32x4*)&Ol[row * 64 + c];
        const f32x4 f1 = *(const f32x4*)&Ol[row * 64 + c + 4];
        union { unsigned u[4]; short8 s8; } uu;
        uu.u[0] = cvtpk(f0[0], f0[1]); uu.u[1] = cvtpk(f0[2], f0[3]);
        uu.u[2] = cvtpk(f1[0], f1[1]); uu.u[3] = cvtpk(f1[2], f1[3]);
        af[st] = uu.s8;
      }
      #pragma unroll
      for (int nt = 0; nt < 4; ++nt) {
        f32x4 dacc = (f32x4){bov[nt], bov[nt], bov[nt], bov[nt]};
        dacc = __builtin_amdgcn_mfma_f32_16x16x32_bf16(af[0], wof[nt][0], dacc, 0, 0, 0);
        dacc = __builtin_amdgcn_mfma_f32_16x16x32_bf16(af[1], wof[nt][1], dacc, 0, 0, 0);
        #pragma unroll
        for (int g = 0; g < 4; ++g) {
          const int nq = q0w + qt * 16 + G * 4 + g;
          out[((size_t)(b * 4096 + nq) * 8 + hh) * 64 + nt * 16 + r15] = dacc[g];
        }
      }
    }
  }
}

extern "C" void kernel_launch(void* const* d_in, const int* in_sizes, int n_in,
                              void* d_out, int out_size, void* d_ws, size_t ws_size,
                              hipStream_t stream) {
  const float* x  = (const float*)d_in[0];
  const float* Wq = (const float*)d_in[1];
  const float* Wk = (const float*)d_in[2];
  const float* Wv = (const float*)d_in[3];
  const float* Wo = (const float*)d_in[4];
  const float* bo = (const float*)d_in[5];

  const size_t NE = 8388608;
  unsigned short* Qw  = (unsigned short*)d_ws;
  unsigned short* Kw  = Qw + NE;
  unsigned short* Vtw = Kw + NE;

  proj_kernel<<<512, 256, 0, stream>>>(x, Wq, Wk, Wv, Qw, Kw, Vtw);
  attn_kernel<<<1024, 128, 0, stream>>>(Qw, Kw, Vtw, Wo, bo, (float*)d_out);
}

// Round 10
// 173.325 us; speedup vs baseline: 1.0896x; 1.0896x over previous
//
#include <hip/hip_runtime.h>
#include <hip/hip_bf16.h>

typedef __attribute__((ext_vector_type(8))) short short8;
typedef __attribute__((ext_vector_type(4))) float f32x4;
typedef __attribute__((ext_vector_type(8))) unsigned short ushort8;
typedef __attribute__((ext_vector_type(2))) unsigned uint2v;

#define LOG2E 1.44269504088896340736f

__device__ __forceinline__ float fexp2(float x) {
#if __has_builtin(__builtin_amdgcn_exp2f)
  return __builtin_amdgcn_exp2f(x);
#else
  return exp2f(x);
#endif
}
__device__ __forceinline__ unsigned cvtpk(float lo, float hi) {
  unsigned r;
  asm("v_cvt_pk_bf16_f32 %0, %1, %2" : "=v"(r) : "v"(lo), "v"(hi));
  return r;
}
__device__ __forceinline__ void pswap32(unsigned &a, unsigned &b) {
#if __has_builtin(__builtin_amdgcn_permlane32_swap)
  uint2v r = __builtin_amdgcn_permlane32_swap(a, b, false, false);
  a = r[0]; b = r[1];
#else
  asm("v_permlane32_swap_b32 %0, %1" : "+v"(a), "+v"(b));
#endif
}
__device__ __forceinline__ void gload_lds16(const unsigned short* g, unsigned short* l) {
  __builtin_amdgcn_global_load_lds(
      (const __attribute__((address_space(1))) unsigned int*)g,
      (__attribute__((address_space(3))) unsigned int*)l, 16, 0, 0);
}
__device__ __forceinline__ int swzK(int r) {
  return ((r & 3) | (((r >> 3) & 1) << 2)) << 3;
}

// ------- MFMA Q/K/V projection; writes Q,K as [bh][n][d], V as V^T [bh][d][n] --
__global__ __launch_bounds__(256) void proj_kernel(
    const float* __restrict__ x,
    const float* __restrict__ Wq, const float* __restrict__ Wk,
    const float* __restrict__ Wv,
    unsigned short* __restrict__ Qo, unsigned short* __restrict__ Ko,
    unsigned short* __restrict__ Vto)
{
  const int tid = threadIdx.x, lane = tid & 63, w = tid >> 6;
  const int r15 = lane & 15, G = lane >> 4;
  const int bh = blockIdx.x >> 4, nt = blockIdx.x & 15;
  const int b = bh >> 3, h = bh & 7;
  const int n0 = nt * 256 + w * 64;

  short8 xf[4][2];
  #pragma unroll
  for (int ct = 0; ct < 4; ++ct) {
    const int n = n0 + ct * 16 + r15;
    const float* xr = x + ((size_t)((b * 4096 + n) * 8 + h)) * 64;
    #pragma unroll
    for (int s = 0; s < 2; ++s) {
      const f32x4 f0 = *(const f32x4*)&xr[s * 32 + G * 8];
      const f32x4 f1 = *(const f32x4*)&xr[s * 32 + G * 8 + 4];
      union { unsigned u[4]; short8 s8; } uu;
      uu.u[0] = cvtpk(f0[0], f0[1]); uu.u[1] = cvtpk(f0[2], f0[3]);
      uu.u[2] = cvtpk(f1[0], f1[1]); uu.u[3] = cvtpk(f1[2], f1[3]);
      xf[ct][s] = uu.s8;
    }
  }

  const size_t obase = (size_t)bh * (4096 * 64);

  #pragma unroll
  for (int wi = 0; wi < 2; ++wi) {
    const float* W = wi ? Wk : Wq;
    unsigned short* O = wi ? Ko : Qo;
    const float sc = wi ? 1.0f : 0.125f * LOG2E;
    short8 wf[4][2];
    #pragma unroll
    for (int ft = 0; ft < 4; ++ft)
      #pragma unroll
      for (int s = 0; s < 2; ++s) {
        union { unsigned u[4]; short8 s8; } uu;
        #pragma unroll
        for (int jj = 0; jj < 4; ++jj) {
          const int k0 = s * 32 + G * 8 + jj * 2;
          uu.u[jj] = cvtpk(W[k0 * 64 + ft * 16 + r15] * sc,
                           W[(k0 + 1) * 64 + ft * 16 + r15] * sc);
        }
        wf[ft][s] = uu.s8;
      }
    f32x4 acc[4][4];
    #pragma unroll
    for (int ft = 0; ft < 4; ++ft)
      #pragma unroll
      for (int ct = 0; ct < 4; ++ct) acc[ft][ct] = (f32x4){0.f, 0.f, 0.f, 0.f};
    #pragma unroll
    for (int s = 0; s < 2; ++s)
      #pragma unroll
      for (int ft = 0; ft < 4; ++ft)
        #pragma unroll
        for (int ct = 0; ct < 4; ++ct)
          acc[ft][ct] = __builtin_amdgcn_mfma_f32_16x16x32_bf16(
              wf[ft][s], xf[ct][s], acc[ft][ct], 0, 0, 0);
    #pragma unroll
    for (int ft = 0; ft < 4; ++ft)
      #pragma unroll
      for (int ct = 0; ct < 4; ++ct) {
        uint2v pk;
        pk[0] = cvtpk(acc[ft][ct][0], acc[ft][ct][1]);
        pk[1] = cvtpk(acc[ft][ct][2], acc[ft][ct][3]);
        *(uint2v*)&O[obase + (size_t)(n0 + ct * 16 + r15) * 64 + ft * 16 + G * 4] = pk;
      }
  }

  {
    short8 wf[4][2];
    #pragma unroll
    for (int ft = 0; ft < 4; ++ft)
      #pragma unroll
      for (int s = 0; s < 2; ++s) {
        union { unsigned u[4]; short8 s8; } uu;
        #pragma unroll
        for (int jj = 0; jj < 4; ++jj) {
          const int k0 = s * 32 + G * 8 + jj * 2;
          uu.u[jj] = cvtpk(Wv[k0 * 64 + ft * 16 + r15], Wv[(k0 + 1) * 64 + ft * 16 + r15]);
        }
        wf[ft][s] = uu.s8;
      }
    f32x4 acc[4][4];
    #pragma unroll
    for (int ct = 0; ct < 4; ++ct)
      #pragma unroll
      for (int ft = 0; ft < 4; ++ft) acc[ct][ft] = (f32x4){0.f, 0.f, 0.f, 0.f};
    #pragma unroll
    for (int s = 0; s < 2; ++s)
      #pragma unroll
      for (int ct = 0; ct < 4; ++ct)
        #pragma unroll
        for (int ft = 0; ft < 4; ++ft)
          acc[ct][ft] = __builtin_amdgcn_mfma_f32_16x16x32_bf16(
              xf[ct][s], wf[ft][s], acc[ct][ft], 0, 0, 0);
    #pragma unroll
    for (int ct = 0; ct < 4; ++ct)
      #pragma unroll
      for (int ft = 0; ft < 4; ++ft) {
        uint2v pk;
        pk[0] = cvtpk(acc[ct][ft][0], acc[ct][ft][1]);
        pk[1] = cvtpk(acc[ct][ft][2], acc[ct][ft][3]);
        *(uint2v*)&Vto[obase + (size_t)(ft * 16 + r15) * 4096 + n0 + ct * 16 + G * 4] = pk;
      }
  }
}

// -------- flash attention, swapped QK^T, static-shift softmax, fused Wo -------
// grid 1024 = 32 bh x 32 qtiles(128). 4 waves x 32 q-rows. KV tile 64, dbuf LDS.
// R8 skeleton + instruction diet: lsum via ones-MFMA, kt-loop unrolled x2 so the
// LDS buffer base folds into ds_read immediates.
__global__ __launch_bounds__(256, 4) void attn_kernel(
    const unsigned short* __restrict__ Q, const unsigned short* __restrict__ K,
    const unsigned short* __restrict__ Vt, const float* __restrict__ Wo,
    const float* __restrict__ bo, float* __restrict__ out)
{
  // 32 KB: [ K dbuf 16KB | V dbuf 16KB ]; reused as 4 x 8KB fp32 O tiles at epilogue
  __shared__ __align__(16) unsigned short SM[16384];

  const int tid = threadIdx.x;
  const int lane = tid & 63, w = tid >> 6;
  const int r15 = lane & 15, G = lane >> 4;

  int bid = blockIdx.x;
  bid = (bid & 7) * 128 + (bid >> 3);          // XCD swizzle (1024 % 8 == 0)
  const int bh = bid >> 5, qt128 = bid & 31;

  const unsigned short* Qb = Q + (size_t)bh * (4096 * 64);
  const unsigned short* Kb = K + (size_t)bh * (4096 * 64);
  const unsigned short* Vb = Vt + (size_t)bh * (64 * 4096);
  const int q0w = qt128 * 128 + w * 32;

  // Q fragments (B-operand layout): lane holds Q[q=lane&15][G*8+j]
  short8 qf[2][2];
  #pragma unroll
  for (int qt = 0; qt < 2; ++qt) {
    const unsigned short* qr = Qb + (size_t)(q0w + qt * 16 + r15) * 64;
    qf[qt][0] = *(const short8*)&qr[G * 8];
    qf[qt][1] = *(const short8*)&qr[32 + G * 8];
  }

  // ones B-fragment (bf16 1.0 everywhere): row-sum of P via the matrix pipe
  short8 ones8;
  {
    union { unsigned short us[8]; short8 s8; } o;
    #pragma unroll
    for (int i = 0; i < 8; ++i) o.us[i] = 0x3F80;
    ones8 = o.s8;
  }

  f32x4 oacc[2][4];
  #pragma unroll
  for (int qt = 0; qt < 2; ++qt)
    #pragma unroll
    for (int t = 0; t < 4; ++t) oacc[qt][t] = (f32x4){0.f, 0.f, 0.f, 0.f};
  f32x4 lacc[2];
  lacc[0] = (f32x4){0.f, 0.f, 0.f, 0.f};
  lacc[1] = (f32x4){0.f, 0.f, 0.f, 0.f};

  // hoisted LDS read offsets
  int kro[4][2], vro[4][2];
  {
    const int Rr = r15 >> 2, gg = r15 & 3;
    #pragma unroll
    for (int t = 0; t < 4; ++t) {
      const int row = gg + ((t & 1) << 2) + ((Rr & 1) << 3) + ((t >> 1) << 4) + ((Rr >> 1) << 5);
      const int sw = swzK(row);
      kro[t][0] = row * 64 + ((G * 8) ^ sw);
      kro[t][1] = row * 64 + ((32 + G * 8) ^ sw);
      const int vrow = t * 16 + r15;
      const int vs = (vrow & 7) << 3;
      vro[t][0] = vrow * 64 + ((G * 8) ^ vs);
      vro[t][1] = vrow * 64 + ((32 + G * 8) ^ vs);
    }
  }

  // staging: 8 segments of 512 elems per tile; wave w owns segs 2w, 2w+1.
  const int seg = w * 2;
  const int kr0 = seg * 8 + (lane >> 3), kr1 = kr0 + 8;
  const int c8 = (lane & 7) * 8;
  const int koff0 = kr0 * 64 + (c8 ^ swzK(kr0));
  const int koff1 = kr1 * 64 + (c8 ^ swzK(kr1));
  const int voff0 = kr0 * 4096 + (c8 ^ ((kr0 & 7) << 3));
  const int voff1 = kr1 * 4096 + (c8 ^ ((kr1 & 7) << 3));

  gload_lds16(Kb + koff0, &SM[seg * 512]);
  gload_lds16(Kb + koff1, &SM[(seg + 1) * 512]);
  gload_lds16(Vb + voff0, &SM[8192 + seg * 512]);
  gload_lds16(Vb + voff1, &SM[8192 + (seg + 1) * 512]);
  __syncthreads();

  // one tile iteration; bufc is a literal at every call site so the LDS base
  // folds into ds_read immediate offsets.
  auto TILE = [&](int bufc, int ktc) {
    if (ktc < 63) {
      const int ko = (ktc + 1) * 4096;
      const int vo = (ktc + 1) * 64;
      unsigned short* kd = &SM[(bufc ^ 1) * 4096];
      unsigned short* vd = &SM[8192 + (bufc ^ 1) * 4096];
      gload_lds16(Kb + ko + koff0, kd + seg * 512);
      gload_lds16(Kb + ko + koff1, kd + (seg + 1) * 512);
      gload_lds16(Vb + vo + voff0, vd + seg * 512);
      gload_lds16(Vb + vo + voff1, vd + (seg + 1) * 512);
    }

    const unsigned short* Kc = &SM[bufc * 4096];
    const unsigned short* Vc = &SM[8192 + bufc * 4096];

    // ---- S = K·Q (static shift: no max subtract; |S| <= ~12 in log2 space) ----
    f32x4 s[2][4];
    #pragma unroll
    for (int t = 0; t < 4; ++t) {
      const short8 kf0 = *(const short8*)&Kc[kro[t][0]];
      const short8 kf1 = *(const short8*)&Kc[kro[t][1]];
      f32x4 z0 = (f32x4){0.f, 0.f, 0.f, 0.f};
      f32x4 z1 = (f32x4){0.f, 0.f, 0.f, 0.f};
      z0 = __builtin_amdgcn_mfma_f32_16x16x32_bf16(kf0, qf[0][0], z0, 0, 0, 0);
      s[0][t] = __builtin_amdgcn_mfma_f32_16x16x32_bf16(kf1, qf[0][1], z0, 0, 0, 0);
      z1 = __builtin_amdgcn_mfma_f32_16x16x32_bf16(kf0, qf[1][0], z1, 0, 0, 0);
      s[1][t] = __builtin_amdgcn_mfma_f32_16x16x32_bf16(kf1, qf[1][1], z1, 0, 0, 0);
    }

    // ---- p = exp2(s); pack; permlane half-exchange (no scalar row-sums) ----
    short8 pa[2][2];
    #pragma unroll
    for (int qt = 0; qt < 2; ++qt) {
      float p[4][4];
      #pragma unroll
      for (int t = 0; t < 4; ++t)
        #pragma unroll
        for (int g = 0; g < 4; ++g) p[t][g] = fexp2(s[qt][t][g]);

      unsigned wA[4], wB[4];
      wA[0] = cvtpk(p[0][0], p[0][1]); wA[1] = cvtpk(p[0][2], p[0][3]);
      wA[2] = cvtpk(p[1][0], p[1][1]); wA[3] = cvtpk(p[1][2], p[1][3]);
      wB[0] = cvtpk(p[2][0], p[2][1]); wB[1] = cvtpk(p[2][2], p[2][3]);
      wB[2] = cvtpk(p[3][0], p[3][1]); wB[3] = cvtpk(p[3][2], p[3][3]);
      union { unsigned u[4]; short8 s8; } fa, fb;
      #pragma unroll
      for (int i = 0; i < 4; ++i) {
        pswap32(wA[i], wB[i]);
        fa.u[i] = wA[i];
        fb.u[i] = wB[i];
      }
      pa[qt][0] = fa.s8;
      pa[qt][1] = fb.s8;
    }

    // ---- lsum on the matrix pipe: lacc[qt] += P · ones ----
    lacc[0] = __builtin_amdgcn_mfma_f32_16x16x32_bf16(pa[0][0], ones8, lacc[0], 0, 0, 0);
    lacc[0] = __builtin_amdgcn_mfma_f32_16x16x32_bf16(pa[0][1], ones8, lacc[0], 0, 0, 0);
    lacc[1] = __builtin_amdgcn_mfma_f32_16x16x32_bf16(pa[1][0], ones8, lacc[1], 0, 0, 0);
    lacc[1] = __builtin_amdgcn_mfma_f32_16x16x32_bf16(pa[1][1], ones8, lacc[1], 0, 0, 0);

    // ---- O += P V ----
    #pragma unroll
    for (int t = 0; t < 4; ++t) {
      const short8 vb0 = *(const short8*)&Vc[vro[t][0]];
      const short8 vb1 = *(const short8*)&Vc[vro[t][1]];
      oacc[0][t] = __builtin_amdgcn_mfma_f32_16x16x32_bf16(pa[0][0], vb0, oacc[0][t], 0, 0, 0);
      oacc[0][t] = __builtin_amdgcn_mfma_f32_16x16x32_bf16(pa[0][1], vb1, oacc[0][t], 0, 0, 0);
      oacc[1][t] = __builtin_amdgcn_mfma_f32_16x16x32_bf16(pa[1][0], vb0, oacc[1][t], 0, 0, 0);
      oacc[1][t] = __builtin_amdgcn_mfma_f32_16x16x32_bf16(pa[1][1], vb1, oacc[1][t], 0, 0, 0);
    }
    __syncthreads();
  };

  for (int kt = 0; kt < 64; kt += 2) {
    TILE(0, kt);
    TILE(1, kt + 1);
  }

  // ---- fused epilogue: normalize -> LDS fp32 tile -> O·Wo + bo -> out ----
  // lacc[qt][g] already holds lsum for q = qt*16 + G*4 + g (no shuffles needed).
  float* Ol = (float*)&SM[0] + w * 2048;   // 32 q x 64 d, XOR-swizzled cols
  #pragma unroll
  for (int qt = 0; qt < 2; ++qt) {
    float li[4];
    #pragma unroll
    for (int g = 0; g < 4; ++g) li[g] = __builtin_amdgcn_rcpf(lacc[qt][g]);
    #pragma unroll
    for (int t = 0; t < 4; ++t)
      #pragma unroll
      for (int g = 0; g < 4; ++g) {
        const int q = qt * 16 + G * 4 + g;
        const int d = t * 16 + r15;
        Ol[q * 64 + (d ^ ((q & 7) << 3))] = oacc[qt][t][g] * li[g];
      }
  }

  // Wo B-frags (bf16) + bias, loaded at epilogue to keep main-loop VGPRs low
  short8 wof[4][2];
  #pragma unroll
  for (int nt = 0; nt < 4; ++nt)
    #pragma unroll
    for (int st = 0; st < 2; ++st) {
      union { unsigned u[4]; short8 s8; } uu;
      #pragma unroll
      for (int jj = 0; jj < 4; ++jj) {
        const int k0 = st * 32 + G * 8 + jj * 2;
        uu.u[jj] = cvtpk(Wo[k0 * 64 + nt * 16 + r15], Wo[(k0 + 1) * 64 + nt * 16 + r15]);
      }
      wof[nt][st] = uu.s8;
    }
  float bov[4];
  #pragma unroll
  for (int nt = 0; nt < 4; ++nt) bov[nt] = bo[nt * 16 + r15];

  const int b = bh >> 3, hh = bh & 7;
  #pragma unroll
  for (int qt2 = 0; qt2 < 2; ++qt2) {
    short8 af[2];
    #pragma unroll
    for (int st = 0; st < 2; ++st) {
      const int row = qt2 * 16 + r15;
      const int c = (st * 32 + G * 8) ^ ((row & 7) << 3);
      const f32x4 f0 = *(const f32x4*)&Ol[row * 64 + c];
      const f32x4 f1 = *(const f32x4*)&Ol[row * 64 + c + 4];
      union { unsigned u[4]; short8 s8; } uu;
      uu.u[0] = cvtpk(f0[0], f0[1]); uu.u[1] = cvtpk(f0[2], f0[3]);
      uu.u[2] = cvtpk(f1[0], f1[1]); uu.u[3] = cvtpk(f1[2], f1[3]);
      af[st] = uu.s8;
    }
    #pragma unroll
    for (int nt = 0; nt < 4; ++nt) {
      f32x4 dacc = (f32x4){bov[nt], bov[nt], bov[nt], bov[nt]};
      dacc = __builtin_amdgcn_mfma_f32_16x16x32_bf16(af[0], wof[nt][0], dacc, 0, 0, 0);
      dacc = __builtin_amdgcn_mfma_f32_16x16x32_bf16(af[1], wof[nt][1], dacc, 0, 0, 0);
      #pragma unroll
      for (int g = 0; g < 4; ++g) {
        const int nq = q0w + qt2 * 16 + G * 4 + g;
        out[((size_t)(b * 4096 + nq) * 8 + hh) * 64 + nt * 16 + r15] = dacc[g];
      }
    }
  }
}

extern "C" void kernel_launch(void* const* d_in, const int* in_sizes, int n_in,
                              void* d_out, int out_size, void* d_ws, size_t ws_size,
                              hipStream_t stream) {
  const float* x  = (const float*)d_in[0];
  const float* Wq = (const float*)d_in[1];
  const float* Wk = (const float*)d_in[2];
  const float* Wv = (const float*)d_in[3];
  const float* Wo = (const float*)d_in[4];
  const float* bo = (const float*)d_in[5];

  const size_t NE = 8388608;
  unsigned short* Qw  = (unsigned short*)d_ws;
  unsigned short* Kw  = Qw + NE;
  unsigned short* Vtw = Kw + NE;

  proj_kernel<<<512, 256, 0, stream>>>(x, Wq, Wk, Wv, Qw, Kw, Vtw);
  attn_kernel<<<1024, 256, 0, stream>>>(Qw, Kw, Vtw, Wo, bo, (float*)d_out);
}